// Round 3
// baseline (1002.720 us; speedup 1.0000x reference)
//
#include <hip/hip_runtime.h>
#include <hip/hip_bf16.h>

typedef __hip_bfloat16 bf16;
typedef __attribute__((ext_vector_type(8))) short bf16x8;   // 8 bf16 = 4 VGPRs (A/B frag)
typedef __attribute__((ext_vector_type(4))) float floatx4;  // C/D frag

#define SCALE 0.17677669529663687f  // 32^-0.5

__device__ __forceinline__ short f2bs(float x) {
  union { bf16 h; short s; } u; u.h = __float2bfloat16(x); return u.s;
}
__device__ __forceinline__ float ldf(const void* p, size_t i, bool f32) {
  return f32 ? ((const float*)p)[i] : __bfloat162float(((const bf16*)p)[i]);
}
__device__ __forceinline__ bf16x8 load8(const void* p, size_t idx, bool f32) {
  if (f32) {
    const float* fp = (const float*)p + idx;
    bf16x8 r;
    #pragma unroll
    for (int i = 0; i < 8; i++) r[i] = f2bs(fp[i]);
    return r;
  }
  return *(const bf16x8*)((const bf16*)p + idx);
}

// ---------- dtype detector: fp32 data viewed as bf16 words has ~44% huge exponents ----------
__global__ void detect_dtype(const unsigned short* __restrict__ q_w_u16, int* __restrict__ flag) {
  int tid = threadIdx.x;  // 64 threads
  int cnt = 0;
  for (int i = tid; i < 4096; i += 64) {
    int e = (q_w_u16[i] >> 7) & 0xFF;
    cnt += (e >= 145);  // |x| >= 2^18: never for N(0,1) bf16
  }
  #pragma unroll
  for (int off = 32; off; off >>= 1) cnt += __shfl_down(cnt, off);
  if (tid == 0) *flag = (cnt >= 16) ? 1 : 0;
}

// ---------- weight transpose: dst[n][k] = src[k][n], K = 256 rows ----------
__global__ __launch_bounds__(256) void transpose_w(const void* __restrict__ src,
                                                   bf16* __restrict__ dst, int N,
                                                   const int* __restrict__ flagp) {
  __shared__ bf16 t[32][33];
  const bool f = (*flagp != 0);
  int bx = blockIdx.x * 32;  // n base
  int by = blockIdx.y * 32;  // k base
  int x = threadIdx.x & 31, y = threadIdx.x >> 5;
  #pragma unroll
  for (int yy = y; yy < 32; yy += 8)
    t[yy][x] = __float2bfloat16(ldf(src, (size_t)(by + yy) * N + bx + x, f));
  __syncthreads();
  #pragma unroll
  for (int yy = y; yy < 32; yy += 8)
    dst[(size_t)(bx + yy) * 256 + by + x] = t[x][yy];
}

// ---------- bias gather-expand: biasFb[h][q][k] = table[rel[q][k]][h] (bf16) ----------
__global__ __launch_bounds__(256) void bias_expand(const void* __restrict__ table,
                                                   const int* __restrict__ relidx,
                                                   bf16* __restrict__ biasFb,
                                                   const int* __restrict__ flagp) {
  const bool f = (*flagp != 0);
  int i = blockIdx.x * 256 + threadIdx.x;  // over 256*576 = 147456
  int idx = relidx[i];
  #pragma unroll
  for (int h = 0; h < 8; h++)
    biasFb[(size_t)h * 147456 + i] = __float2bfloat16(ldf(table, (size_t)idx * 8 + h, f));
}

// ---------- GEMM: C[m][n] = A[a_off + m][0:256] . BT[n][0:256] + bias[n] ----------
// EPI 0: store to C (d_out, dtype per flag) at c_off, row stride 256   (out proj)
// EPI 1: store bf16 (v*SCALE), row stride 256                          (q proj)
// EPI 2: ncol<256 -> Kb[m][256] bf16; ncol>=256 -> Vt[w][h][d][n] bf16 (kv proj)
// A dtype: EPI==0 -> always bf16 (internal); else per flag.
template <int EPI>
__global__ __launch_bounds__(256) void gemm_bt(const void* __restrict__ A, size_t a_off,
                                               const bf16* __restrict__ BT,
                                               const void* __restrict__ bias,
                                               void* __restrict__ C, size_t c_off,
                                               bf16* __restrict__ C2,
                                               const int* __restrict__ flagp) {
  __shared__ __align__(16) bf16 As[128 * 40];  // +8 pad kills b128 bank conflicts
  __shared__ __align__(16) bf16 Bs[128 * 40];
  const bool f = (*flagp != 0);
  const bool af = (EPI == 0) ? false : f;  // A dtype (Obuf is internal bf16)
  const int tid = threadIdx.x;
  const int wave = tid >> 6, lane = tid & 63;
  const int q4 = lane >> 4, l16 = lane & 15;
  const int m0 = blockIdx.x * 128, n0 = blockIdx.y * 128;
  const int wm = (wave & 1) * 64, wn = (wave >> 1) * 64;  // 2x2 waves of 64x64
  const int sr = tid >> 2, sc = (tid & 3) * 8;
  floatx4 acc[4][4];
  #pragma unroll
  for (int i = 0; i < 4; i++)
    #pragma unroll
    for (int j = 0; j < 4; j++) acc[i][j] = (floatx4){0.f, 0.f, 0.f, 0.f};

  const size_t abase = a_off + (size_t)(m0 + sr) * 256 + sc;
  const bf16* Bp = BT + (size_t)(n0 + sr) * 256 + sc;
  for (int k0 = 0; k0 < 256; k0 += 32) {
    *(bf16x8*)&As[sr * 40 + sc]        = load8(A, abase + k0, af);
    *(bf16x8*)&As[(sr + 64) * 40 + sc] = load8(A, abase + 64 * 256 + k0, af);
    *(bf16x8*)&Bs[sr * 40 + sc]        = *(const bf16x8*)(Bp + k0);
    *(bf16x8*)&Bs[(sr + 64) * 40 + sc] = *(const bf16x8*)(Bp + 64 * 256 + k0);
    __syncthreads();
    bf16x8 afr[4], bfr[4];
    #pragma unroll
    for (int i = 0; i < 4; i++)
      afr[i] = *(const bf16x8*)&As[(wm + i * 16 + l16) * 40 + q4 * 8];
    #pragma unroll
    for (int j = 0; j < 4; j++)
      bfr[j] = *(const bf16x8*)&Bs[(wn + j * 16 + l16) * 40 + q4 * 8];
    #pragma unroll
    for (int i = 0; i < 4; i++)
      #pragma unroll
      for (int j = 0; j < 4; j++)
        acc[i][j] = __builtin_amdgcn_mfma_f32_16x16x32_bf16(afr[i], bfr[j], acc[i][j], 0, 0, 0);
    __syncthreads();
  }
  // epilogue: lane holds rows quad*4+r, col lane&15 of each 16x16 tile
  #pragma unroll
  for (int i = 0; i < 4; i++) {
    #pragma unroll
    for (int j = 0; j < 4; j++) {
      int mrow = m0 + wm + i * 16 + q4 * 4;
      int ncol = n0 + wn + j * 16 + l16;
      float bv = ldf(bias, ncol, f);
      #pragma unroll
      for (int r = 0; r < 4; r++) {
        float v = acc[i][j][r] + bv;
        int m_e = mrow + r;
        if (EPI == 0) {
          size_t oi = c_off + (size_t)m_e * 256 + ncol;
          if (f) ((float*)C)[oi] = v;
          else   ((bf16*)C)[oi] = __float2bfloat16(v);
        } else if (EPI == 1) {
          ((bf16*)C)[(size_t)m_e * 256 + ncol] = __float2bfloat16(v * SCALE);
        } else {
          if (ncol < 256) {
            ((bf16*)C)[(size_t)m_e * 256 + ncol] = __float2bfloat16(v);
          } else {
            int cc = ncol - 256;
            int hh = cc >> 5, dd = cc & 31;
            int bb = m_e / 576;            // chunk-local window
            int nn = m_e - bb * 576;
            C2[(((size_t)bb * 8 + hh) * 32 + dd) * 576 + nn] = __float2bfloat16(v);
          }
        }
      }
    }
  }
}

// ---------- attention: block = (w, h, 64 q-rows), wave = 16 q-rows ----------
// Q/Kb/Vt/O chunk-local bf16; biasFb global [8][256][576] bf16.
__global__ __launch_bounds__(256) void attn(const bf16* __restrict__ Q,     // [W*256][256] pre-scaled
                                            const bf16* __restrict__ Kb,    // [W*576][256]
                                            const bf16* __restrict__ Vt,    // [W][8][32][576]
                                            const bf16* __restrict__ biasF, // [8][256][576]
                                            bf16* __restrict__ O) {         // [W*256][256]
  __shared__ __align__(16) bf16 P[4][16][296];  // per-wave 16 x 288 (+8 pad)
  const int tid = threadIdx.x, wave = tid >> 6, lane = tid & 63;
  const int q4 = lane >> 4, l16 = lane & 15;
  const int blk = blockIdx.x;
  const int b = blk >> 5, h = (blk >> 2) & 7, qc = blk & 3;
  const int q0 = qc * 64 + wave * 16;

  // Q A-frag: row = lane&15, k(d) = quad*8+j  (one 16B load)
  bf16x8 qf = *(const bf16x8*)&Q[((size_t)b * 256 + q0 + l16) * 256 + h * 32 + q4 * 8];

  // ---- S = Q.K^T + bias, full 576 row in registers ----
  float S[36][4];
  const bf16* kp = Kb + (size_t)b * 576 * 256 + h * 32 + q4 * 8;
  const bf16* bp = biasF + ((size_t)h * 256 + q0 + q4 * 4) * 576 + l16;
  #pragma unroll
  for (int t = 0; t < 36; t++) {
    bf16x8 kf = *(const bf16x8*)(kp + (size_t)(t * 16 + l16) * 256);
    floatx4 c;
    c[0] = __bfloat162float(bp[t * 16 + 0 * 576]);
    c[1] = __bfloat162float(bp[t * 16 + 1 * 576]);
    c[2] = __bfloat162float(bp[t * 16 + 2 * 576]);
    c[3] = __bfloat162float(bp[t * 16 + 3 * 576]);
    floatx4 s = __builtin_amdgcn_mfma_f32_16x16x32_bf16(qf, kf, c, 0, 0, 0);
    #pragma unroll
    for (int r = 0; r < 4; r++) S[t][r] = s[r];
  }
  // ---- softmax along 576: lane holds cols l16+16t of rows q4*4+r ----
  #pragma unroll
  for (int r = 0; r < 4; r++) {
    float mx = S[0][r];
    #pragma unroll
    for (int t = 1; t < 36; t++) mx = fmaxf(mx, S[t][r]);
    #pragma unroll
    for (int off = 1; off < 16; off <<= 1) mx = fmaxf(mx, __shfl_xor(mx, off, 16));
    float sum = 0.f;
    #pragma unroll
    for (int t = 0; t < 36; t++) {
      float p = __expf(S[t][r] - mx);
      S[t][r] = p;
      sum += p;
    }
    #pragma unroll
    for (int off = 1; off < 16; off <<= 1) sum += __shfl_xor(sum, off, 16);
    float inv = 1.f / sum;
    #pragma unroll
    for (int t = 0; t < 36; t++) S[t][r] *= inv;
  }
  // ---- O = P.V via LDS round-trip (D-layout -> A-layout), two 288-col halves ----
  floatx4 o0 = (floatx4){0.f, 0.f, 0.f, 0.f};
  floatx4 o1 = (floatx4){0.f, 0.f, 0.f, 0.f};
  const bf16* vp = Vt + ((size_t)b * 8 + h) * 32 * 576;
  #pragma unroll
  for (int half = 0; half < 2; half++) {
    #pragma unroll
    for (int t = 0; t < 18; t++)
      #pragma unroll
      for (int r = 0; r < 4; r++)
        P[wave][q4 * 4 + r][t * 16 + l16] = __float2bfloat16(S[half * 18 + t][r]);
    __syncthreads();
    #pragma unroll
    for (int kc = 0; kc < 9; kc++) {
      int kg = half * 9 + kc;
      bf16x8 pf = *(const bf16x8*)&P[wave][l16][kc * 32 + q4 * 8];
      bf16x8 v0 = *(const bf16x8*)(vp + (size_t)l16 * 576 + kg * 32 + q4 * 8);
      bf16x8 v1 = *(const bf16x8*)(vp + (size_t)(l16 + 16) * 576 + kg * 32 + q4 * 8);
      o0 = __builtin_amdgcn_mfma_f32_16x16x32_bf16(pf, v0, o0, 0, 0, 0);
      o1 = __builtin_amdgcn_mfma_f32_16x16x32_bf16(pf, v1, o1, 0, 0, 0);
    }
    __syncthreads();
  }
  bf16* op = O + ((size_t)b * 256 + q0 + q4 * 4) * 256 + h * 32;
  #pragma unroll
  for (int r = 0; r < 4; r++) {
    op[(size_t)r * 256 + l16]      = __float2bfloat16(o0[r]);
    op[(size_t)r * 256 + 16 + l16] = __float2bfloat16(o1[r]);
  }
}

extern "C" void kernel_launch(void* const* d_in, const int* in_sizes, int n_in,
                              void* d_out, int out_size, void* d_ws, size_t ws_size,
                              hipStream_t stream) {
  const void* q_w    = d_in[0];
  const void* kv_w   = d_in[1];
  const void* q_Wm   = d_in[2];
  const void* q_b    = d_in[3];
  const void* kv_Wm  = d_in[4];
  const void* kv_b   = d_in[5];
  const void* proj_Wm= d_in[6];
  const void* proj_b = d_in[7];
  const void* btab   = d_in[8];
  const int*  relidx = (const int*)d_in[9];

  // ---- workspace layout (element offsets are dtype-agnostic) ----
  // flag 256 | WqT 131072 | WkvT 262144 | WpT 131072 | biasFb 2359296 | chunk buffers
  const size_t FIXED = 256 + 131072 + 262144 + 131072 + 2359296;  // 2,883,840
  int W = 2;
  {
    const int cand[8] = {256, 128, 64, 32, 16, 8, 4, 2};
    for (int i = 0; i < 8; i++) {
      if (ws_size >= FIXED + (size_t)cand[i] * 851968ULL) { W = cand[i]; break; }
    }
  }
  const int NCH = 256 / W;

  char* ws = (char*)d_ws;
  int*  flag  = (int*)(ws);
  bf16* WqT   = (bf16*)(ws + 256);
  bf16* WkvT  = (bf16*)(ws + 131328);
  bf16* WpT   = (bf16*)(ws + 393472);
  bf16* biasFb= (bf16*)(ws + 524544);
  char* cb    = ws + FIXED;
  const size_t qsz = (size_t)W * 131072ULL;   // W*256*256*2
  const size_t ksz = (size_t)W * 294912ULL;   // W*576*256*2
  bf16* Qs   = (bf16*)(cb);
  bf16* Kb   = (bf16*)(cb + qsz);
  bf16* Vt   = (bf16*)(cb + qsz + ksz);
  bf16* Obuf = (bf16*)(cb + qsz + 2 * ksz);

  detect_dtype<<<1, 64, 0, stream>>>((const unsigned short*)q_w, flag);
  transpose_w<<<dim3(8, 8),  256, 0, stream>>>(q_Wm,   WqT,  256, flag);
  transpose_w<<<dim3(16, 8), 256, 0, stream>>>(kv_Wm,  WkvT, 512, flag);
  transpose_w<<<dim3(8, 8),  256, 0, stream>>>(proj_Wm,WpT,  256, flag);
  bias_expand<<<576, 256, 0, stream>>>(btab, relidx, biasFb, flag);

  for (int c = 0; c < NCH; c++) {
    const size_t qoff = (size_t)c * W * 65536;    // elements
    const size_t koff = (size_t)c * W * 147456;   // elements
    // q projection (+scale): M = W*256, N = 256
    gemm_bt<1><<<dim3(2 * W, 2), 256, 0, stream>>>(q_w, qoff, WqT, q_b, Qs, 0, nullptr, flag);
    // kv projection: M = W*576, N = 512 (W even -> grid integral)
    gemm_bt<2><<<dim3((W * 576) / 128, 4), 256, 0, stream>>>(kv_w, koff, WkvT, kv_b, Kb, 0, Vt, flag);
    // attention: W windows * 8 heads * 4 q-chunks
    attn<<<W * 32, 256, 0, stream>>>(Qs, Kb, Vt, biasFb, Obuf);
    // output projection: M = W*256, N = 256, store dtype per flag
    gemm_bt<0><<<dim3(2 * W, 2), 256, 0, stream>>>(Obuf, 0, WpT, proj_b, d_out, qoff, nullptr, flag);
  }
}